// Round 8
// baseline (1316.087 us; speedup 1.0000x reference)
//
#include <hip/hip_runtime.h>
#include <math.h>

// Sinkhorn loss, B=8, S=2048, P=1024, D=2, eps=0.01, 50 iters.
// PERSISTENT-KERNEL v8 — 8 waves/SIMD (2 blocks/CU) + split-tile waves with
// LDS partial-LSE merge.
// R7 evidence: VALUBusy 17/48/64% at 1/2/4 waves/SIMD with constant VALU-busy
// time ~330-390us => still latency-bound; VGPR=48 unlocks 2 blocks/CU.
// 512 blocks x 1024 thr. Per batch: 64 contiguous blocks (deadlock-safe even
// at 1 blk/CU residency: 256 resident = 4 whole batches). Block owns 32 f-rows
// / 16 g-cols. To keep LDS reuse at 4B/elem with half the rows, waves split
// the tile scan: f = 8 rowgroups x 2 halves, g = 4 colgroups x 4 quarters;
// per-wave partial (M - c0, S) merged via a 512B LDS array (c0 folded into M
// so the merge needs no per-lane-indexed constant arrays -> no scratch).
// f/g constants recomputed per-iter from L1-hot loads (persistent regs ~15).
// Base-2 scaled potentials: F2 = f/(eps*ln2), G2 = g/(eps*ln2), K = 100*log2(e)
//   f elem: u = 2K*x.y + (G2[p] - K*y2[p]);  F2 = (K*x2 - log2 S) - LSE2(u)
//   g elem: u = 2K*x.y + (F2[s] - K*x2[s]);  G2 = (K*y2 + logb2) - LSE2(u)

#define BB 8
#define SS 2048
#define PP 1024
#define NEG_INF -1e9f
#define LOG2S 11.0f
#define ITERS 50
#define K2E 144.269504088896f   /* 100*log2(e) */
#define TWOK 288.539008177792f  /* 200*log2(e) */
#define NBLK 512
#define NTHR 1024

__device__ __forceinline__ float fexp2(float x) {
  return __builtin_amdgcn_exp2f(x);
}
__device__ __forceinline__ float flog2(float x) {
  return __builtin_amdgcn_logf(x);
}

// agent-scope coherent (cache-bypassing) accessors, RELAXED only (proven R6/R7)
__device__ __forceinline__ float coh_load(const float* p) {
  return __hip_atomic_load((float*)p, __ATOMIC_RELAXED, __HIP_MEMORY_SCOPE_AGENT);
}
__device__ __forceinline__ void coh_store(float* p, float v) {
  __hip_atomic_store(p, v, __ATOMIC_RELAXED, __HIP_MEMORY_SCOPE_AGENT);
}
__device__ __forceinline__ int coh_loadi(const int* p) {
  return __hip_atomic_load((int*)p, __ATOMIC_RELAXED, __HIP_MEMORY_SCOPE_AGENT);
}
__device__ __forceinline__ void coh_storei(int* p, int v) {
  __hip_atomic_store(p, v, __ATOMIC_RELAXED, __HIP_MEMORY_SCOPE_AGENT);
}

// 64-block per-batch barrier, RMW-free: block stores its phase to its own
// slot; wave 0 polls all 64 slots (one per lane) until __all >= phase.
__device__ __forceinline__ void batch_barrier(int* slots, int sub, int phase,
                                              int w, int lane) {
  __syncthreads();
  asm volatile("" ::: "memory");
  if (threadIdx.x == 0) coh_storei(&slots[sub], phase);
  if (w == 0) {
    for (;;) {
      int v = coh_loadi(&slots[lane]);
      if (__all(v >= phase)) break;
      __builtin_amdgcn_s_sleep(1);
    }
  }
  asm volatile("" ::: "memory");
  __syncthreads();
}

// ws layout (bytes):
//   G2    : [0,      32768)   B*P float
//   F2    : [32768,  98304)   B*S float
//   logb2 : [98304, 131072)   B*P float
//   slots : [131072, 133120)  8 batches x 64 ints (phase slots)

__global__ __launch_bounds__(1024) void setup_kernel(
    const int* __restrict__ labels, float* __restrict__ G2,
    float* __restrict__ logb2, int* __restrict__ slots,
    float* __restrict__ out) {
  __shared__ int c[PP];
  int b = blockIdx.x;
  int t = threadIdx.x;  // 1024 threads
  c[t] = 0;
  __syncthreads();
  atomicAdd(&c[labels[b * SS + t] & (PP - 1)], 1);
  atomicAdd(&c[labels[b * SS + PP + t] & (PP - 1)], 1);
  __syncthreads();
  int cc = c[t];
  logb2[b * PP + t] = (cc > 0) ? (flog2((float)cc) - LOG2S) : NEG_INF;
  G2[b * PP + t] = 0.0f;
  if (t < 64) slots[(b << 6) + t] = 0;
  if (t == 0 && b == 0) out[0] = 0.0f;
}

__global__ __launch_bounds__(1024) void sinkhorn_persist(
    const float* __restrict__ preds, const float* __restrict__ pos,
    const float* __restrict__ logb2, float* __restrict__ F2g,
    float* __restrict__ G2g, int* __restrict__ slots,
    float* __restrict__ out) {
  __shared__ float4 shf[1032];   // (y0, y1, qy = G2 - K*y2, pad), +16B pad /128
  __shared__ float4 shg[2064];   // (x0, x1, qx = F2 - K*x2, pad), +16B pad /128
  __shared__ float2 part[16][4]; // per-wave partial (M - c0, S)
  __shared__ float spart;
  const int t = threadIdx.x;    // 1024 threads, 16 waves
  const int blk = blockIdx.x;   // 512 blocks = 2/CU target
  const int bb = blk >> 6;      // 64 blocks per batch (contiguous!)
  const int sub = blk & 63;
  int* myslots = slots + (bb << 6);
  const float2* pos2 = (const float2*)pos;
  const float2* preds2 = (const float2*)preds;
  float* G2b = G2g + (bb << 10);
  float* F2b = F2g + (bb << 11);

  // ---- persistent init: x/y constants into LDS + K-scaled norms in regs
  float yr2, xr2[2];
  {
    float2 y = pos2[(bb << 10) + t];
    yr2 = y.x * y.x + y.y * y.y;
    shf[t + (t >> 7)] = make_float4(y.x, y.y, 0.0f, 0.0f);
  }
#pragma unroll
  for (int k = 0; k < 2; ++k) {
    int e = t + (k << 10);
    float2 x = preds2[(bb << 11) + e];
    xr2[k] = x.x * x.x + x.y * x.y;
    shg[e + (e >> 7)] = make_float4(x.x, x.y, 0.0f, 0.0f);
  }

  const int w = t >> 6, lane = t & 63;
  // f: wave = (rowgroup rg, tile-half th); 4 rows, 8 reads over half tile
  const int rg = w >> 1, th = w & 1;
  const int frowb = (bb << 11) + (sub << 5) + (rg << 2);
  // g: wave = (colgroup cg, tile-quarter tq); 4 cols, 8 reads over quarter
  const int cg = w >> 2, tq = w & 3;
  const int gcolb = (bb << 10) + (sub << 4) + (cg << 2);

  for (int it = 0; it < ITERS; ++it) {
    // ---- stage qy = G2 - K*y2 (4KB agent-scope reads)
    shf[t + (t >> 7)].z = fmaf(-K2E, yr2, coh_load(&G2b[t]));
    __syncthreads();
    // ---- f-compute: 4 rows/wave over half tile, online LSE
    {
      float fk0[4], fk1[4], fc0[4];
#pragma unroll
      for (int r = 0; r < 4; ++r) {
        float2 fx = preds2[frowb + r];  // L1-hot, wave-uniform
        fk0[r] = TWOK * fx.x;
        fk1[r] = TWOK * fx.y;
        fc0[r] = fmaf(K2E, fx.x * fx.x + fx.y * fx.y, -LOG2S);
      }
      float m[4], s[4];
#pragma unroll
      for (int r = 0; r < 4; ++r) { m[r] = -3.4e38f; s[r] = 0.0f; }
#pragma unroll
      for (int ch = 0; ch < 2; ++ch) {
        float4 a[4];
#pragma unroll
        for (int i = 0; i < 4; ++i) {
          int e = (th << 9) + (((ch << 2) + i) << 6) + lane;
          a[i] = shf[e + (e >> 7)];
        }
#pragma unroll
        for (int r = 0; r < 4; ++r) {
          float u0 = fmaf(fk0[r], a[0].x, fmaf(fk1[r], a[0].y, a[0].z));
          float u1 = fmaf(fk0[r], a[1].x, fmaf(fk1[r], a[1].y, a[1].z));
          float u2 = fmaf(fk0[r], a[2].x, fmaf(fk1[r], a[2].y, a[2].z));
          float u3 = fmaf(fk0[r], a[3].x, fmaf(fk1[r], a[3].y, a[3].z));
          float cm = fmaxf(fmaxf(u0, u1), fmaxf(u2, u3));
          float mn = fmaxf(m[r], cm);
          float sc = fexp2(m[r] - mn);
          float sum = (fexp2(u0 - mn) + fexp2(u1 - mn)) +
                      (fexp2(u2 - mn) + fexp2(u3 - mn));
          s[r] = fmaf(s[r], sc, sum);
          m[r] = mn;
        }
      }
      // lane butterfly -> per-wave (M, S); fold fc0 into M for the merge
      float2 myp = make_float2(0.0f, 0.0f);
#pragma unroll
      for (int r = 0; r < 4; ++r) {
        float M = m[r];
#pragma unroll
        for (int off = 1; off <= 32; off <<= 1)
          M = fmaxf(M, __shfl_xor(M, off, 64));
        float sr = s[r] * fexp2(m[r] - M);
#pragma unroll
        for (int off = 1; off <= 32; off <<= 1) sr += __shfl_xor(sr, off, 64);
        if (lane == r) myp = make_float2(M - fc0[r], sr);
      }
      if (lane < 4) part[w][lane] = myp;
    }
    __syncthreads();
    // merge the two tile-halves, coalesced store by lanes 0..3
    if (th == 0 && lane < 4) {
      float2 p0 = part[w][lane];
      float2 p1 = part[w + 1][lane];
      float M = fmaxf(p0.x, p1.x);
      float S = p0.y * fexp2(p0.x - M) + p1.y * fexp2(p1.x - M);
      coh_store(&F2g[frowb + lane], -M - flog2(S));
    }
    batch_barrier(myslots, sub, 2 * it + 1, w, lane);

    // ---- stage qx = F2 - K*x2 (8KB agent-scope reads)
#pragma unroll
    for (int k = 0; k < 2; ++k) {
      int e = t + (k << 10);
      shg[e + (e >> 7)].z = fmaf(-K2E, xr2[k], coh_load(&F2b[e]));
    }
    __syncthreads();
    // ---- g-compute: 4 cols/wave over quarter tile, online LSE
    {
      float gk0[4], gk1[4], gc0[4];
#pragma unroll
      for (int c = 0; c < 4; ++c) {
        float2 gy = pos2[gcolb + c];  // L1-hot, wave-uniform
        gk0[c] = TWOK * gy.x;
        gk1[c] = TWOK * gy.y;
        gc0[c] = fmaf(K2E, gy.x * gy.x + gy.y * gy.y, logb2[gcolb + c]);
      }
      float m[4], s[4];
#pragma unroll
      for (int c = 0; c < 4; ++c) { m[c] = -3.4e38f; s[c] = 0.0f; }
#pragma unroll
      for (int ch = 0; ch < 2; ++ch) {
        float4 a[4];
#pragma unroll
        for (int i = 0; i < 4; ++i) {
          int e = (tq << 9) + (((ch << 2) + i) << 6) + lane;
          a[i] = shg[e + (e >> 7)];
        }
#pragma unroll
        for (int c = 0; c < 4; ++c) {
          float u0 = fmaf(gk0[c], a[0].x, fmaf(gk1[c], a[0].y, a[0].z));
          float u1 = fmaf(gk0[c], a[1].x, fmaf(gk1[c], a[1].y, a[1].z));
          float u2 = fmaf(gk0[c], a[2].x, fmaf(gk1[c], a[2].y, a[2].z));
          float u3 = fmaf(gk0[c], a[3].x, fmaf(gk1[c], a[3].y, a[3].z));
          float cm = fmaxf(fmaxf(u0, u1), fmaxf(u2, u3));
          float mn = fmaxf(m[c], cm);
          float sc = fexp2(m[c] - mn);
          float sum = (fexp2(u0 - mn) + fexp2(u1 - mn)) +
                      (fexp2(u2 - mn) + fexp2(u3 - mn));
          s[c] = fmaf(s[c], sc, sum);
          m[c] = mn;
        }
      }
      float2 myp = make_float2(0.0f, 0.0f);
#pragma unroll
      for (int c = 0; c < 4; ++c) {
        float M = m[c];
#pragma unroll
        for (int off = 1; off <= 32; off <<= 1)
          M = fmaxf(M, __shfl_xor(M, off, 64));
        float sr = s[c] * fexp2(m[c] - M);
#pragma unroll
        for (int off = 1; off <= 32; off <<= 1) sr += __shfl_xor(sr, off, 64);
        if (lane == c) myp = make_float2(M - gc0[c], sr);
      }
      if (lane < 4) part[w][lane] = myp;
    }
    __syncthreads();
    // merge the four tile-quarters, coalesced store by lanes 0..3
    if (tq == 0 && lane < 4) {
      float2 p0 = part[w][lane];
      float2 p1 = part[w + 1][lane];
      float2 p2 = part[w + 2][lane];
      float2 p3 = part[w + 3][lane];
      float M = fmaxf(fmaxf(p0.x, p1.x), fmaxf(p2.x, p3.x));
      float S = p0.y * fexp2(p0.x - M) + p1.y * fexp2(p1.x - M) +
                p2.y * fexp2(p2.x - M) + p3.y * fexp2(p3.x - M);
      coh_store(&G2g[gcolb + lane], -M - flog2(S));
    }
    batch_barrier(myslots, sub, 2 * it + 2, w, lane);
  }

  // ---- fused final: restage qy with final G2, rowsum over own 32 rows
  if (t == 0) spart = 0.0f;
  shf[t + (t >> 7)].z = fmaf(-K2E, yr2, coh_load(&G2b[t]));
  __syncthreads();
  float acc = 0.0f;
#pragma unroll
  for (int rr = 0; rr < 2; ++rr) {
    int row = (bb << 11) + (sub << 5) + (w << 1) + rr;
    float2 x = preds2[row];
    float x2 = x.x * x.x + x.y * x.y;
    float qx = fmaf(-K2E, x2, coh_load(&F2g[row]));
#pragma unroll
    for (int i = 0; i < 16; ++i) {
      int p = (i << 6) + lane;
      float4 a = shf[p + (p >> 7)];
      float y2 = fmaf(a.x, a.x, a.y * a.y);
      float tt = fmaf(x.y, a.y, x.x * a.x);
      float c = fmaxf(x2 + y2 - 2.0f * tt, 0.0f);  // clamped cost
      float v2 = fmaf(TWOK, tt, a.z + qx);         // -K*C' + F2 + G2 (base-2)
      acc = fmaf(fexp2(v2), c, acc);               // c==0 kills C'<0 case
    }
  }
#pragma unroll
  for (int off = 32; off; off >>= 1) acc += __shfl_xor(acc, off, 64);
  if (lane == 0) atomicAdd(&spart, acc);
  __syncthreads();
  if (t == 0) atomicAdd(out, spart * (1.0f / (float)BB));
}

extern "C" void kernel_launch(void* const* d_in, const int* in_sizes, int n_in,
                              void* d_out, int out_size, void* d_ws,
                              size_t ws_size, hipStream_t stream) {
  const float* preds = (const float*)d_in[0];  // [B,S,2]
  const int* labels = (const int*)d_in[1];     // [B,S]
  const float* pos = (const float*)d_in[2];    // [B,P,2]
  float* out = (float*)d_out;
  char* ws = (char*)d_ws;
  float* G2 = (float*)(ws);
  float* F2 = (float*)(ws + 32768);
  float* logb2 = (float*)(ws + 98304);
  int* slots = (int*)(ws + 131072);

  hipLaunchKernelGGL(setup_kernel, dim3(BB), dim3(1024), 0, stream, labels, G2,
                     logb2, slots, out);
  hipLaunchKernelGGL(sinkhorn_persist, dim3(NBLK), dim3(NTHR), 0, stream,
                     preds, pos, logb2, F2, G2, slots, out);
}

// Round 9
// 566.993 us; speedup vs baseline: 2.3212x; 2.3212x over previous
//
#include <hip/hip_runtime.h>
#include <math.h>

// Sinkhorn loss, B=8, S=2048, P=1024, D=2, eps=0.01, 50 iters.
// PERSISTENT-KERNEL v9 — R7 skeleton + SoA LDS + packed-f32 (v_pk_*) math.
// R8 lesson: 1024-thr/50KB blocks never dual-occupy a CU (occupancy pinned
// 49%, dur 2x => sequential halves) — occupancy axis is closed at 4 w/SIMD.
// R3..R7 invariant: VALU-busy TIME ~330-390us at ~5.3 VALU ops/elem — cut
// the instruction stream instead. CDNA4 v_pk_fma/max/add_f32 process elem
// PAIRS; SoA LDS arrays (y0/y1/q) make each ds_read_b64 a ready pk operand
// pair (also -25% LDS bytes; 2-way bank alias is free). Online-max LSE kept
// (deferred shift rejected: F2 units amplify potential swings x144 -> exp2
// range overflow risk). Barrier/staging/decomposition = R7 verbatim.
// Base-2 scaled potentials: F2 = f/(eps*ln2), G2 = g/(eps*ln2), K = 100*log2(e)
//   f elem: u = 2K*x.y + (G2[p] - K*y2[p]);  F2 = (K*x2 - log2 S) - LSE2(u)
//   g elem: u = 2K*x.y + (F2[s] - K*x2[s]);  G2 = (K*y2 + logb2) - LSE2(u)

#define BB 8
#define SS 2048
#define PP 1024
#define NEG_INF -1e9f
#define LOG2S 11.0f
#define ITERS 50
#define K2E 144.269504088896f   /* 100*log2(e) */
#define TWOK 288.539008177792f  /* 200*log2(e) */
#define NBLK 256
#define NTHR 1024

typedef float v2f __attribute__((ext_vector_type(2)));

__device__ __forceinline__ float fexp2(float x) {
  return __builtin_amdgcn_exp2f(x);
}
__device__ __forceinline__ float flog2(float x) {
  return __builtin_amdgcn_logf(x);
}
__device__ __forceinline__ v2f vfma(v2f a, v2f b, v2f c) {
  return __builtin_elementwise_fma(a, b, c);
}
__device__ __forceinline__ v2f vmax(v2f a, v2f b) {
  return __builtin_elementwise_max(a, b);
}

// agent-scope coherent (cache-bypassing) accessors, RELAXED only (proven R6/R7)
__device__ __forceinline__ float coh_load(const float* p) {
  return __hip_atomic_load((float*)p, __ATOMIC_RELAXED, __HIP_MEMORY_SCOPE_AGENT);
}
__device__ __forceinline__ void coh_store(float* p, float v) {
  __hip_atomic_store(p, v, __ATOMIC_RELAXED, __HIP_MEMORY_SCOPE_AGENT);
}
__device__ __forceinline__ int coh_loadi(const int* p) {
  return __hip_atomic_load((int*)p, __ATOMIC_RELAXED, __HIP_MEMORY_SCOPE_AGENT);
}
__device__ __forceinline__ void coh_storei(int* p, int v) {
  __hip_atomic_store(p, v, __ATOMIC_RELAXED, __HIP_MEMORY_SCOPE_AGENT);
}

// 32-block per-batch barrier, RMW-free (proven R7): block stores its phase to
// its own slot; wave 0 polls the 32 slots (one per lane) until __all >= phase.
__device__ __forceinline__ void batch_barrier(int* slots, int sub, int phase,
                                              int w, int lane) {
  __syncthreads();
  asm volatile("" ::: "memory");
  if (threadIdx.x == 0) coh_storei(&slots[sub], phase);
  if (w == 0) {
    for (;;) {
      int v = (lane < 32) ? coh_loadi(&slots[lane]) : 0x7fffffff;
      if (__all(v >= phase)) break;
      __builtin_amdgcn_s_sleep(1);
    }
  }
  asm volatile("" ::: "memory");
  __syncthreads();
}

// ws layout (bytes):
//   G2    : [0,      32768)   B*P float
//   F2    : [32768,  98304)   B*S float
//   logb2 : [98304, 131072)   B*P float
//   slots : [131072, 132096)  8 batches x 32 ints (phase slots)

__global__ __launch_bounds__(1024) void setup_kernel(
    const int* __restrict__ labels, float* __restrict__ G2,
    float* __restrict__ logb2, int* __restrict__ slots,
    float* __restrict__ out) {
  __shared__ int c[PP];
  int b = blockIdx.x;
  int t = threadIdx.x;  // 1024 threads
  c[t] = 0;
  __syncthreads();
  atomicAdd(&c[labels[b * SS + t] & (PP - 1)], 1);
  atomicAdd(&c[labels[b * SS + PP + t] & (PP - 1)], 1);
  __syncthreads();
  int cc = c[t];
  logb2[b * PP + t] = (cc > 0) ? (flog2((float)cc) - LOG2S) : NEG_INF;
  G2[b * PP + t] = 0.0f;
  if (t < 32) slots[(b << 5) + t] = 0;
  if (t == 0 && b == 0) out[0] = 0.0f;
}

__global__ __launch_bounds__(1024) void sinkhorn_persist(
    const float* __restrict__ preds, const float* __restrict__ pos,
    const float* __restrict__ logb2, float* __restrict__ F2g,
    float* __restrict__ G2g, int* __restrict__ slots,
    float* __restrict__ out) {
  // SoA LDS tiles: element-pair reads are pk-ready reg pairs
  __shared__ __align__(16) float fy0[PP], fy1[PP], fq[PP];        // 12 KB
  __shared__ __align__(16) float gx0[SS], gx1[SS], gq[SS];        // 24 KB
  __shared__ float spart;
  const int t = threadIdx.x;    // 1024 threads, 16 waves
  const int blk = blockIdx.x;   // 256 blocks = 1/CU (proven geometry)
  const int bb = blk >> 5;      // 32 blocks per batch
  const int sub = blk & 31;
  int* myslots = slots + (bb << 5);
  const float2* pos2 = (const float2*)pos;
  const float2* preds2 = (const float2*)preds;
  float* G2b = G2g + (bb << 10);
  float* F2b = F2g + (bb << 11);

  // ---- persistent init: x/y constants into LDS + K-scaled norms in regs
  float yr2, xr2[2];
  {
    float2 y = pos2[(bb << 10) + t];
    yr2 = y.x * y.x + y.y * y.y;
    fy0[t] = y.x;
    fy1[t] = y.y;
  }
#pragma unroll
  for (int k = 0; k < 2; ++k) {
    int e = t + (k << 10);
    float2 x = preds2[(bb << 11) + e];
    xr2[k] = x.x * x.x + x.y * x.y;
    gx0[e] = x.x;
    gx1[e] = x.y;
  }

  const int w = t >> 6, lane = t & 63;
  // f-phase: wave w owns 4 rows [blk*64 + w*4, +4); lane scans 8 elem-pairs
  const int frowb = (blk << 6) + (w << 2);
  float fk0[4], fk1[4], fc0[4];
#pragma unroll
  for (int r = 0; r < 4; ++r) {
    float2 fx = preds2[frowb + r];  // wave-uniform broadcast load
    fk0[r] = TWOK * fx.x;
    fk1[r] = TWOK * fx.y;
    fc0[r] = fmaf(K2E, fx.x * fx.x + fx.y * fx.y, -LOG2S);
  }
  // g-phase: wave w owns 2 cols [blk*32 + w*2, +2); lane scans 16 elem-pairs
  const int gcolb = (blk << 5) + (w << 1);
  float gk0[2], gk1[2], gc0[2];
#pragma unroll
  for (int c = 0; c < 2; ++c) {
    float2 gy = pos2[gcolb + c];
    gk0[c] = TWOK * gy.x;
    gk1[c] = TWOK * gy.y;
    gc0[c] = fmaf(K2E, gy.x * gy.x + gy.y * gy.y, logb2[gcolb + c]);
  }

  for (int it = 0; it < ITERS; ++it) {
    // ---- stage qy = G2 - K*y2 (4KB agent-scope reads, stride-1 LDS writes)
    fq[t] = fmaf(-K2E, yr2, coh_load(&G2b[t]));
    __syncthreads();
    // ---- f-compute: online LSE over pairs, 4 rows/lane, pk math
    {
      float m[4];
      v2f s[4];
#pragma unroll
      for (int r = 0; r < 4; ++r) { m[r] = -3.4e38f; s[r] = (v2f)(0.0f); }
#pragma unroll
      for (int ch = 0; ch < 2; ++ch) {
        v2f a0[4], a1[4], aq[4];
#pragma unroll
        for (int i = 0; i < 4; ++i) {
          int pi = (ch << 8) + (i << 6) + lane;  // pair index, consecutive
          a0[i] = *(const v2f*)&fy0[pi << 1];
          a1[i] = *(const v2f*)&fy1[pi << 1];
          aq[i] = *(const v2f*)&fq[pi << 1];
        }
#pragma unroll
        for (int r = 0; r < 4; ++r) {
          v2f K0 = (v2f)(fk0[r]), K1 = (v2f)(fk1[r]);
          v2f u0 = vfma(K0, a0[0], vfma(K1, a1[0], aq[0]));
          v2f u1 = vfma(K0, a0[1], vfma(K1, a1[1], aq[1]));
          v2f u2 = vfma(K0, a0[2], vfma(K1, a1[2], aq[2]));
          v2f u3 = vfma(K0, a0[3], vfma(K1, a1[3], aq[3]));
          v2f cm2 = vmax(vmax(u0, u1), vmax(u2, u3));
          float mn = fmaxf(m[r], fmaxf(cm2.x, cm2.y));
          float sc = fexp2(m[r] - mn);
          v2f mn2 = (v2f)(mn);
          v2f d0 = u0 - mn2, d1 = u1 - mn2, d2 = u2 - mn2, d3 = u3 - mn2;
          v2f e0 = {fexp2(d0.x), fexp2(d0.y)};
          v2f e1 = {fexp2(d1.x), fexp2(d1.y)};
          v2f e2 = {fexp2(d2.x), fexp2(d2.y)};
          v2f e3 = {fexp2(d3.x), fexp2(d3.y)};
          s[r] = vfma(s[r], (v2f)(sc), (e0 + e1) + (e2 + e3));
          m[r] = mn;
        }
      }
      // lane merge + coalesced store: lane r keeps value r, lanes 0..3 store
      float fout = 0.0f;
#pragma unroll
      for (int r = 0; r < 4; ++r) {
        float M = m[r];
#pragma unroll
        for (int off = 1; off <= 32; off <<= 1)
          M = fmaxf(M, __shfl_xor(M, off, 64));
        float sr = (s[r].x + s[r].y) * fexp2(m[r] - M);
#pragma unroll
        for (int off = 1; off <= 32; off <<= 1) sr += __shfl_xor(sr, off, 64);
        float v = fc0[r] - M - flog2(sr);
        if (lane == r) fout = v;
      }
      if (lane < 4) coh_store(&F2g[frowb + lane], fout);
    }
    batch_barrier(myslots, sub, 2 * it + 1, w, lane);

    // ---- stage qx = F2 - K*x2 (8KB agent-scope reads)
#pragma unroll
    for (int k = 0; k < 2; ++k) {
      int e = t + (k << 10);
      gq[e] = fmaf(-K2E, xr2[k], coh_load(&F2b[e]));
    }
    __syncthreads();
    // ---- g-compute: online LSE over pairs, 2 cols/lane, pk math
    {
      float m[2];
      v2f s[2];
#pragma unroll
      for (int c = 0; c < 2; ++c) { m[c] = -3.4e38f; s[c] = (v2f)(0.0f); }
#pragma unroll
      for (int ch = 0; ch < 4; ++ch) {
        v2f a0[4], a1[4], aq[4];
#pragma unroll
        for (int i = 0; i < 4; ++i) {
          int pi = (ch << 8) + (i << 6) + lane;
          a0[i] = *(const v2f*)&gx0[pi << 1];
          a1[i] = *(const v2f*)&gx1[pi << 1];
          aq[i] = *(const v2f*)&gq[pi << 1];
        }
#pragma unroll
        for (int c = 0; c < 2; ++c) {
          v2f K0 = (v2f)(gk0[c]), K1 = (v2f)(gk1[c]);
          v2f u0 = vfma(K0, a0[0], vfma(K1, a1[0], aq[0]));
          v2f u1 = vfma(K0, a0[1], vfma(K1, a1[1], aq[1]));
          v2f u2 = vfma(K0, a0[2], vfma(K1, a1[2], aq[2]));
          v2f u3 = vfma(K0, a0[3], vfma(K1, a1[3], aq[3]));
          v2f cm2 = vmax(vmax(u0, u1), vmax(u2, u3));
          float mn = fmaxf(m[c], fmaxf(cm2.x, cm2.y));
          float sc = fexp2(m[c] - mn);
          v2f mn2 = (v2f)(mn);
          v2f d0 = u0 - mn2, d1 = u1 - mn2, d2 = u2 - mn2, d3 = u3 - mn2;
          v2f e0 = {fexp2(d0.x), fexp2(d0.y)};
          v2f e1 = {fexp2(d1.x), fexp2(d1.y)};
          v2f e2 = {fexp2(d2.x), fexp2(d2.y)};
          v2f e3 = {fexp2(d3.x), fexp2(d3.y)};
          s[c] = vfma(s[c], (v2f)(sc), (e0 + e1) + (e2 + e3));
          m[c] = mn;
        }
      }
      float gout = 0.0f;
#pragma unroll
      for (int c = 0; c < 2; ++c) {
        float M = m[c];
#pragma unroll
        for (int off = 1; off <= 32; off <<= 1)
          M = fmaxf(M, __shfl_xor(M, off, 64));
        float sr = (s[c].x + s[c].y) * fexp2(m[c] - M);
#pragma unroll
        for (int off = 1; off <= 32; off <<= 1) sr += __shfl_xor(sr, off, 64);
        float v = gc0[c] - M - flog2(sr);
        if (lane == c) gout = v;
      }
      if (lane < 2) coh_store(&G2g[gcolb + lane], gout);
    }
    batch_barrier(myslots, sub, 2 * it + 2, w, lane);
  }

  // ---- fused final: restage qy with final G2, rowsum over own 64 rows
  if (t == 0) spart = 0.0f;
  fq[t] = fmaf(-K2E, yr2, coh_load(&G2b[t]));
  __syncthreads();
  float acc = 0.0f;
#pragma unroll
  for (int rr = 0; rr < 4; ++rr) {
    int row = frowb + rr;
    float2 x = preds2[row];
    float x2 = x.x * x.x + x.y * x.y;
    float qx = fmaf(-K2E, x2, coh_load(&F2g[row]));
#pragma unroll
    for (int i = 0; i < 16; ++i) {
      int p = (i << 6) + lane;
      float ay0 = fy0[p], ay1 = fy1[p], aqz = fq[p];
      float y2 = fmaf(ay0, ay0, ay1 * ay1);
      float tt = fmaf(x.y, ay1, x.x * ay0);
      float c = fmaxf(x2 + y2 - 2.0f * tt, 0.0f);  // clamped cost
      float v2 = fmaf(TWOK, tt, aqz + qx);         // -K*C' + F2 + G2 (base-2)
      acc = fmaf(fexp2(v2), c, acc);               // c==0 kills C'<0 case
    }
  }
#pragma unroll
  for (int off = 32; off; off >>= 1) acc += __shfl_xor(acc, off, 64);
  if (lane == 0) atomicAdd(&spart, acc);
  __syncthreads();
  if (t == 0) atomicAdd(out, spart * (1.0f / (float)BB));
}

extern "C" void kernel_launch(void* const* d_in, const int* in_sizes, int n_in,
                              void* d_out, int out_size, void* d_ws,
                              size_t ws_size, hipStream_t stream) {
  const float* preds = (const float*)d_in[0];  // [B,S,2]
  const int* labels = (const int*)d_in[1];     // [B,S]
  const float* pos = (const float*)d_in[2];    // [B,P,2]
  float* out = (float*)d_out;
  char* ws = (char*)d_ws;
  float* G2 = (float*)(ws);
  float* F2 = (float*)(ws + 32768);
  float* logb2 = (float*)(ws + 98304);
  int* slots = (int*)(ws + 131072);

  hipLaunchKernelGGL(setup_kernel, dim3(BB), dim3(1024), 0, stream, labels, G2,
                     logb2, slots, out);
  hipLaunchKernelGGL(sinkhorn_persist, dim3(NBLK), dim3(NTHR), 0, stream,
                     preds, pos, logb2, F2, G2, slots, out);
}